// Round 1
// 494.098 us; speedup vs baseline: 1.1181x; 1.1181x over previous
//
#include <hip/hip_runtime.h>
#include <hip/hip_bf16.h>
#include <math.h>

// Problem constants (from reference)
#define NEXP 8
#define DIM_D 1024
#define DIM_H 4096
#define NB 4096

typedef __attribute__((ext_vector_type(8))) short short8;
typedef __attribute__((ext_vector_type(4))) float floatx4;

__device__ __forceinline__ unsigned short f2bf(float x) {
  __hip_bfloat16 h = __float2bfloat16(x);   // RNE
  unsigned short u;
  __builtin_memcpy(&u, &h, 2);
  return u;
}
__device__ __forceinline__ unsigned int pack2bf(float a, float b) {
  return (unsigned int)f2bf(a) | ((unsigned int)f2bf(b) << 16);
}

// async global->LDS, 16B per lane; LDS dest = wave-uniform base + lane*16
__device__ __forceinline__ void async_copy16(const void* g, void* l) {
  __builtin_amdgcn_global_load_lds(
      (const __attribute__((address_space(1))) unsigned int*)g,
      (__attribute__((address_space(3))) unsigned int*)l, 16, 0, 0);
}

// ---------------- setup: bucket rows by expert (f32 t, bit-exact vs ref) ----
__global__ void setup_kernel(const float* __restrict__ t,
                             int* __restrict__ offs, int* __restrict__ perm) {
  __shared__ int cnt[NEXP];
  __shared__ int cur[NEXP];
  const int tid = threadIdx.x;
  if (tid < NEXP) cnt[tid] = 0;
  __syncthreads();
  for (int i = tid; i < NB; i += 256) {
    int e = (int)(t[i] * 8.0f);             // t/H_STEP, pow2 -> exact
    e = e < 0 ? 0 : (e > NEXP - 1 ? NEXP - 1 : e);
    atomicAdd(&cnt[e], 1);
  }
  __syncthreads();
  if (tid == 0) {
    int s = 0;
    for (int e = 0; e < NEXP; ++e) { offs[e] = s; cur[e] = s; s += cnt[e]; }
    offs[NEXP] = s;
  }
  __syncthreads();
  for (int i = tid; i < NB; i += 256) {
    int e = (int)(t[i] * 8.0f);
    e = e < 0 ? 0 : (e > NEXP - 1 ? NEXP - 1 : e);
    int slot = atomicAdd(&cur[e], 1);
    perm[slot] = i;
  }
}

// ---------------- f32 -> bf16 bulk convert (for y) ----------------
__global__ __launch_bounds__(256)
void cvt_kernel(const float* __restrict__ in, __hip_bfloat16* __restrict__ out) {
  const long long i = ((long long)blockIdx.x * 256 + threadIdx.x) * 8;
  const float4 a = *(const float4*)(in + i);
  const float4 b = *(const float4*)(in + i + 4);
  unsigned int r[4];
  r[0] = pack2bf(a.x, a.y);
  r[1] = pack2bf(a.z, a.w);
  r[2] = pack2bf(b.x, b.y);
  r[3] = pack2bf(b.z, b.w);
  *(uint4*)(out + i) = *(const uint4*)r;
}

// ------- f32 transpose + bf16 convert: in [R][C] f32 -> out [C][R] bf16 ----
// 64x64 tile as a pure u32-word transpose: each u32 packs an in-row PAIR
// (rows 2m, 2m+1) at one column -> exactly one out-row u32 word.
// LDS [32 pairs][69] u32; stride 69 (== 5 mod 32) makes BOTH the 16 scalar
// writes and the 8 scalar reads per thread 2-way-max bank access (free).
__global__ __launch_bounds__(256)
void transpose_cvt_kernel(const float* __restrict__ in,
                          __hip_bfloat16* __restrict__ out, int R, int C) {
  __shared__ unsigned int wbuf[32 * 69];
  const long long base = (long long)blockIdx.z * R * C;
  const int c0 = blockIdx.x * 64;
  const int r0 = blockIdx.y * 64;
  const int t = threadIdx.x;
  {
    const int p = t >> 3, g = t & 7;      // row-pair p, 8-col group g
    const float* s0 = in + base + (long long)(r0 + 2 * p) * C + c0 + g * 8;
    const float4 a0 = *(const float4*)(s0);
    const float4 a1 = *(const float4*)(s0 + 4);
    const float4 b0 = *(const float4*)(s0 + C);
    const float4 b1v = *(const float4*)(s0 + C + 4);
    unsigned int* dp = &wbuf[p * 69 + g * 8];
    dp[0] = pack2bf(a0.x, b0.x);
    dp[1] = pack2bf(a0.y, b0.y);
    dp[2] = pack2bf(a0.z, b0.z);
    dp[3] = pack2bf(a0.w, b0.w);
    dp[4] = pack2bf(a1.x, b1v.x);
    dp[5] = pack2bf(a1.y, b1v.y);
    dp[6] = pack2bf(a1.z, b1v.z);
    dp[7] = pack2bf(a1.w, b1v.w);
  }
  __syncthreads();
  {
    const int oc = t >> 2, rq = t & 3;    // out row c0+oc, word group rq
    __align__(16) unsigned int res[8];
#pragma unroll
    for (int j = 0; j < 8; ++j) res[j] = wbuf[(rq * 8 + j) * 69 + oc];
    __hip_bfloat16* dstp = out + base + (long long)(c0 + oc) * R + r0 + rq * 16;
    *(uint4*)dstp = *(const uint4*)&res[0];
    *(uint4*)(dstp + 8) = *(const uint4*)&res[4];
  }
}

// ---------------- grouped NT GEMM, 2-phase pipelined ----------------
// C[m][n] = sum_k A[m][k] * BT[n][k]; 128x128 tile, BK=64, double-buffered
// LDS (2 x 32KB), global_load_lds(16B) staging of the NEXT K-tile issued
// BEFORE computing the current one (load latency hides under ds_read+MFMA),
// single __syncthreads per K-tile.
// LDS tiling per tile: [cgrp=k/32][row][4x16B] -> frag read 16B-chunk slot is
// (4*row + fq) mod 8: uniform over the wave => bank-conflict-free ds_read_b128.
// Staged source is permuted to match (4 lanes read 64 contiguous bytes/row).
// 4 waves (2x2), each 64x64 output = acc[4][4] of 16x16x32 MFMA.
// MODE 0: A = y_bf16 (rows via perm), epilogue tanh(x+b1) -> hid bf16 (permuted)
// MODE 1: A = hid (contiguous rows), epilogue full output -> f32 out[perm[i]]
template <int MODE>
__global__ __launch_bounds__(256, 2)
void gemm_kernel(const __hip_bfloat16* __restrict__ A,
                 const __hip_bfloat16* __restrict__ BT,   // [E][N][K] bf16
                 const float* __restrict__ bias,          // [E][N] f32
                 const int* __restrict__ offs, const int* __restrict__ perm,
                 void* __restrict__ dstv,                 // MODE0: bf16*, MODE1: f32*
                 const float* __restrict__ yin,           // [B][N] f32 (MODE 1)
                 const float* __restrict__ scales,        // [N] f32 (MODE 1)
                 const float* __restrict__ shifta,
                 const float* __restrict__ shiftb,
                 int K, int N) {
  const int e  = blockIdx.y >> 5;
  const int mt = blockIdx.y & 31;
  const int off = offs[e];
  const int cnt = offs[e + 1] - off;
  const int m0 = mt * 128;
  if (m0 >= cnt) return;                    // early-exit for padded grid
  const int rows = min(128, cnt - m0);
  const int n0 = blockIdx.x * 128;

  // [2 buf][ A 16KB | B 16KB ]  = 64 KB
  __shared__ __align__(16) char lds[65536];

  const int tid = threadIdx.x;
  const int w = tid >> 6, l = tid & 63;

  // ---- staging source pointers: 4 A-chunks + 4 B-chunks per thread/K-tile
  // linear LDS chunk c = j*256+tid ; c -> (cgrp=c>>9, row=(c>>2)&127, c2=c&3)
  const __hip_bfloat16* aptr[4];
  const __hip_bfloat16* bptr[4];
#pragma unroll
  for (int j = 0; j < 4; ++j) {
    const int chunk = j * 256 + tid;
    const int cgrp = chunk >> 9;
    const int row  = (chunk >> 2) & 127;
    const int c2   = chunk & 3;
    const int ra = row < rows ? row : rows - 1;   // clamp: stage valid memory
    const long long ga = (MODE == 0) ? (long long)perm[off + m0 + ra]
                                     : (long long)(off + m0 + ra);
    aptr[j] = A + ga * K + cgrp * 32 + c2 * 8;
    bptr[j] = BT + ((long long)e * N + n0 + row) * K + cgrp * 32 + c2 * 8;
  }

  floatx4 acc[4][4];
#pragma unroll
  for (int i = 0; i < 4; ++i)
#pragma unroll
    for (int j = 0; j < 4; ++j) acc[i][j] = (floatx4){0.f, 0.f, 0.f, 0.f};

  const int wm = w >> 1, wn = w & 1;
  const int fr = l & 15;                    // M (A) / N (B) index in fragment
  const int fq = l >> 4;                    // K 16B-sub-chunk in fragment
  const int ldsA = (wm * 64 + fr) * 64 + fq * 16;
  const int ldsB = 16384 + (wn * 64 + fr) * 64 + fq * 16;

  const int nt = K >> 6;                    // K-tiles of 64

  // prologue: stage K-tile 0 into buf 0
#pragma unroll
  for (int j = 0; j < 4; ++j) {
    async_copy16(aptr[j], lds + j * 4096 + w * 1024);
    async_copy16(bptr[j], lds + 16384 + j * 4096 + w * 1024);
    aptr[j] += 64; bptr[j] += 64;
  }
  __syncthreads();

  for (int t = 0; t < nt; ++t) {
    const int cur = (t & 1) << 15;
    if (t + 1 < nt) {                       // stage NEXT K-tile first
      const int nxt = cur ^ 32768;
#pragma unroll
      for (int j = 0; j < 4; ++j) {
        async_copy16(aptr[j], lds + nxt + j * 4096 + w * 1024);
        async_copy16(bptr[j], lds + nxt + 16384 + j * 4096 + w * 1024);
        aptr[j] += 64; bptr[j] += 64;
      }
    }
    short8 af[2][4], bf[2][4];
#pragma unroll
    for (int ks = 0; ks < 2; ++ks) {
#pragma unroll
      for (int mi = 0; mi < 4; ++mi)
        af[ks][mi] = *(const short8*)(lds + cur + ks * 8192 + mi * 1024 + ldsA);
#pragma unroll
      for (int ni = 0; ni < 4; ++ni)
        bf[ks][ni] = *(const short8*)(lds + cur + ks * 8192 + ni * 1024 + ldsB);
    }
#pragma unroll
    for (int ks = 0; ks < 2; ++ks)
#pragma unroll
      for (int mi = 0; mi < 4; ++mi)
#pragma unroll
        for (int ni = 0; ni < 4; ++ni)
          acc[mi][ni] = __builtin_amdgcn_mfma_f32_16x16x32_bf16(
              af[ks][mi], bf[ks][ni], acc[mi][ni], 0, 0, 0);
    if (t + 1 < nt) __syncthreads();        // drains the prefetch + LDS reuse
  }

  float av = 0.f, bv = 0.f;
  if (MODE == 1) {
    const float sa = 1.f / (1.f + expf(-shifta[0]));
    const float sb = 1.f / (1.f + expf(-shiftb[0]));
    av = 0.0f + sa * (-1.0f - 0.0f);         // EIGINIT + sig*(EIGMIN-EIGINIT)
    bv = 0.0f + sb * (1.0f - 0.0f);          // EIGINIT + sig*(EIGMAX-EIGINIT)
  }

  // C/D layout: col = lane&15, row = (lane>>4)*4 + reg
#pragma unroll
  for (int mi = 0; mi < 4; ++mi) {
#pragma unroll
    for (int r = 0; r < 4; ++r) {
      const int rl = wm * 64 + mi * 16 + fq * 4 + r;
      if (rl >= rows) continue;
      const int i = off + m0 + rl;
      const int orig = (MODE == 1) ? perm[i] : 0;
#pragma unroll
      for (int ni = 0; ni < 4; ++ni) {
        const int cg = n0 + wn * 64 + ni * 16 + fr;
        const float x = acc[mi][ni][r] + bias[e * N + cg];
        if (MODE == 0) {
          ((__hip_bfloat16*)dstv)[(long long)i * N + cg] = __float2bfloat16(tanhf(x));
        } else {
          const float sc = 1.f / (1.f + expf(-scales[cg]));
          const float yv = yin[(long long)orig * N + cg];
          const float res = 0.5f * ((bv - av) * sc * x + (av + bv) * yv);
          ((float*)dstv)[(long long)orig * N + cg] = res;   // f32 output!
        }
      }
    }
  }
}

extern "C" void kernel_launch(void* const* d_in, const int* in_sizes, int n_in,
                              void* d_out, int out_size, void* d_ws, size_t ws_size,
                              hipStream_t stream) {
  const float* t      = (const float*)d_in[0];
  const float* y      = (const float*)d_in[1];
  const float* W1     = (const float*)d_in[2];
  const float* b1     = (const float*)d_in[3];
  const float* W2     = (const float*)d_in[4];
  const float* b2     = (const float*)d_in[5];
  const float* scales = (const float*)d_in[6];
  const float* shifta = (const float*)d_in[7];
  const float* shiftb = (const float*)d_in[8];

  // ws layout: [0,64MB)   transposed bf16 weights (W1T, then reused for W2T)
  //            [64,96MB)  hid bf16 [NB][DIM_H], permuted row order
  //            [96,104MB) y_bf16 [NB][DIM_D]
  //            [104MB,..) offs[16] + perm[NB]
  char* ws = (char*)d_ws;
  __hip_bfloat16* WT  = (__hip_bfloat16*)ws;
  __hip_bfloat16* hid = (__hip_bfloat16*)(ws + (size_t)64 * 1024 * 1024);
  __hip_bfloat16* ybf = (__hip_bfloat16*)(ws + (size_t)96 * 1024 * 1024);
  int* offs = (int*)(ws + (size_t)104 * 1024 * 1024);
  int* perm = offs + 16;

  setup_kernel<<<1, 256, 0, stream>>>(t, offs, perm);

  cvt_kernel<<<(NB * DIM_D) / (256 * 8), 256, 0, stream>>>(y, ybf);

  // W1 [E][D][DH] f32 -> WT [E][DH][D] bf16
  transpose_cvt_kernel<<<dim3(DIM_H / 64, DIM_D / 64, NEXP), 256, 0, stream>>>(
      W1, WT, DIM_D, DIM_H);
  // hid = tanh(y @ W1 + b1), grouped by expert
  gemm_kernel<0><<<dim3(DIM_H / 128, NEXP * 32), 256, 0, stream>>>(
      ybf, WT, b1, offs, perm, hid, nullptr, nullptr, nullptr, nullptr,
      DIM_D, DIM_H);
  // W2 [E][DH][D] f32 -> WT [E][D][DH] bf16 (safe reuse: stream-ordered)
  transpose_cvt_kernel<<<dim3(DIM_D / 64, DIM_H / 64, NEXP), 256, 0, stream>>>(
      W2, WT, DIM_H, DIM_D);
  // out = 0.5*((b-a)*sig(scales)*(hid@W2+b2) + (a+b)*y), scattered via perm
  gemm_kernel<1><<<dim3(DIM_D / 128, NEXP * 32), 256, 0, stream>>>(
      hid, WT, b2, offs, perm, d_out, y, scales, shifta, shiftb,
      DIM_H, DIM_D);
}